// Round 9
// baseline (728.676 us; speedup 1.0000x reference)
//
#include <hip/hip_runtime.h>

#define IN_DIM 512
#define OUT_DIM 32
#define KSTEPS 10
#define ALPHA 0.1f
#define SCB 512      // scan block chunk

typedef __attribute__((ext_vector_type(8))) short short8;    // 8 bf16 (4 VGPRs)
typedef __attribute__((ext_vector_type(4))) float floatx4;   // MFMA acc
typedef _Float16 fp16x8 __attribute__((ext_vector_type(8))); // 16B packed fp16

// ---------------- degree / norm / chunked-CSR build ----------------
// 4 src-chunk buckets per dst node (L2 windowing for the pull gathers).
// y-substitution (y = dinv*z) removes per-edge weights: csr entry is just
// the prescaled byte offset src*64 (4B).

__global__ void k_count(const int* __restrict__ src, const int* __restrict__ dst,
                        int* __restrict__ cnt, int E, int cdiv) {
    int e = blockIdx.x * blockDim.x + threadIdx.x;
    if (e < E) {
        int ch = src[e] / cdiv;
        atomicAdd(&cnt[dst[e] * 4 + ch], 1);
    }
}

__global__ void k_rsqrt(const int* __restrict__ cnt, float* __restrict__ dinv, int N) {
    int i = blockIdx.x * blockDim.x + threadIdx.x;
    if (i < N) {
        int d = cnt[4 * i] + cnt[4 * i + 1] + cnt[4 * i + 2] + cnt[4 * i + 3];
        dinv[i] = rsqrtf((float)d + 1.0f);  // +1 self-loop
    }
}

// ---------------- parallel exclusive scan (3 phases) ----------------

__global__ __launch_bounds__(SCB) void k_bsum(const int* __restrict__ v,
                                              int* __restrict__ bsum, int M) {
    __shared__ int s[SCB];
    int i = blockIdx.x * SCB + threadIdx.x;
    s[threadIdx.x] = (i < M) ? v[i] : 0;
    __syncthreads();
    for (int d = SCB / 2; d > 0; d >>= 1) {
        if (threadIdx.x < d) s[threadIdx.x] += s[threadIdx.x + d];
        __syncthreads();
    }
    if (threadIdx.x == 0) bsum[blockIdx.x] = s[0];
}

__global__ __launch_bounds__(1024) void k_bscan(const int* __restrict__ bsum,
                                                int* __restrict__ bsum_off,
                                                int* __restrict__ total_out, int NB) {
    __shared__ int s[1024];
    int t = threadIdx.x;
    s[t] = (t < NB) ? bsum[t] : 0;
    __syncthreads();
    for (int d = 1; d < 1024; d <<= 1) {
        int v = (t >= d) ? s[t - d] : 0;
        __syncthreads();
        s[t] += v;
        __syncthreads();
    }
    if (t < NB) bsum_off[t] = (t == 0) ? 0 : s[t - 1];
    if (t == 0 && total_out) *total_out = s[1023];
}

__global__ __launch_bounds__(SCB) void k_boff(const int* __restrict__ v,
                                              const int* __restrict__ bsum_off,
                                              int* __restrict__ off, int M) {
    __shared__ int s[SCB];
    int t = threadIdx.x;
    int i = blockIdx.x * SCB + t;
    int myv = (i < M) ? v[i] : 0;
    s[t] = myv;
    __syncthreads();
    for (int d = 1; d < SCB; d <<= 1) {
        int u = (t >= d) ? s[t - d] : 0;
        __syncthreads();
        s[t] += u;
        __syncthreads();
    }
    if (i < M) off[i] = bsum_off[blockIdx.x] + s[t] - myv;  // exclusive
}

// csr entry: byte offset of src y-row (src*64). No weights (y-substitution).
__global__ void k_fill(const int* __restrict__ src, const int* __restrict__ dst,
                       const int* __restrict__ off4,
                       int* __restrict__ cur, int* __restrict__ csrI, int E, int cdiv) {
    int e = blockIdx.x * blockDim.x + threadIdx.x;
    if (e < E) {
        int d = dst[e], s = src[e];
        int key = d * 4 + s / cdiv;
        int pos = off4[key] + atomicAdd(&cur[key], 1);
        csrI[pos] = s * (OUT_DIM * 2);
    }
}

// ---------------- bf16 split helpers ----------------

__device__ inline unsigned bf16_rne(float f) {
    unsigned u = __float_as_uint(f);
    return (u + 0x7FFFu + ((u >> 16) & 1u)) >> 16;
}

__global__ void k_wsplit(const float* __restrict__ W, short* __restrict__ Wh,
                         short* __restrict__ Wl, int M) {
    int i = blockIdx.x * blockDim.x + threadIdx.x;
    if (i < M) {
        float f = W[i];
        unsigned hb = bf16_rne(f);
        float fh = __uint_as_float(hb << 16);
        unsigned lb = bf16_rne(f - fh);
        Wh[i] = (short)hb;
        Wl[i] = (short)lb;
    }
}

__device__ inline void split8v(float4 v0, float4 v1, short8& hi, short8& lo) {
    float f0 = v0.x, f1 = v0.y, f2 = v0.z, f3 = v0.w;
    float f4 = v1.x, f5 = v1.y, f6 = v1.z, f7 = v1.w;
    float fv[8] = {f0, f1, f2, f3, f4, f5, f6, f7};
#pragma unroll
    for (int j = 0; j < 8; j++) {
        unsigned hb = bf16_rne(fv[j]);
        float fh = __uint_as_float(hb << 16);
        unsigned lb = bf16_rne(fv[j] - fh);
        hi[j] = (short)hb;
        lo[j] = (short)lb;
    }
}

// ---------------- dense projection: LDS-staged bf16-split MFMA ----------------
// (structure unchanged — passed. Epilogue now also writes y0 = dinv*h (fp16
//  seed) and hy = ALPHA*dinv*h (fp16), plus h fp32 for the final step.)

__global__ __launch_bounds__(256) void k_gemm5(const float* __restrict__ x,
                                               const short* __restrict__ Wh,
                                               const short* __restrict__ Wl,
                                               const float* __restrict__ bias,
                                               const float* __restrict__ dinv,
                                               float* __restrict__ h,
                                               _Float16* __restrict__ y0,
                                               _Float16* __restrict__ hy, int N) {
    __shared__ float lds[64 * 128];  // 32 KB, per-wave partitioned
    const int t = threadIdx.x;
    const int wave = t >> 6, lane = t & 63;
    const int m = lane & 15, quad = lane >> 4;
    const int rowBase = blockIdx.x * 64;
    const int ls = lane >> 5;
    const int sw = lane & 31;

    int ro0, ro1, ro2, ro3, ro4, ro5, ro6, ro7;
    {
        int r;
#define MKRO(i, v)                                                  \
        r = rowBase + wave * 16 + (i) * 2 + ls;                     \
        if (r >= N) r = N - 1;                                      \
        v = r * (IN_DIM * 4);
        MKRO(0, ro0) MKRO(1, ro1) MKRO(2, ro2) MKRO(3, ro3)
        MKRO(4, ro4) MKRO(5, ro5) MKRO(6, ro6) MKRO(7, ro7)
#undef MKRO
    }
    const char* xbase = (const char*)x + sw * 16;

    char* lwb = (char*)lds;
    int wo0, wo1, wo2, wo3, wo4, wo5, wo6, wo7;
    {
        int lr;
#define MKWO(i, v)                                                  \
        lr = wave * 16 + (i) * 2 + ls;                              \
        v = lr * 512 + ((sw * 16) ^ ((lr & 7) << 4));
        MKWO(0, wo0) MKWO(1, wo1) MKWO(2, wo2) MKWO(3, wo3)
        MKWO(4, wo4) MKWO(5, wo5) MKWO(6, wo6) MKWO(7, wo7)
#undef MKWO
    }

    const int key = (m & 7) << 4;
    const char* ra0 = (const char*)lds + (wave * 16 + m) * 512 + ((quad * 32) ^ key);
    const char* ra1 = (const char*)lds + (wave * 16 + m) * 512 + ((quad * 32 + 16) ^ key);

    const short* w0h = Wh + (size_t)m * IN_DIM + quad * 8;
    const short* w0l = Wl + (size_t)m * IN_DIM + quad * 8;
    const short* w1h = Wh + (size_t)(m + 16) * IN_DIM + quad * 8;
    const short* w1l = Wl + (size_t)(m + 16) * IN_DIM + quad * 8;

    floatx4 acc0 = {0.f, 0.f, 0.f, 0.f};
    floatx4 acc1 = {0.f, 0.f, 0.f, 0.f};

    float4 n0, n1, n2, n3, n4, n5, n6, n7;

#define LOADCH(ch) do {                                             \
        const char* xb = xbase + (ch) * 512;                        \
        n0 = *(const float4*)(xb + ro0);                            \
        n1 = *(const float4*)(xb + ro1);                            \
        n2 = *(const float4*)(xb + ro2);                            \
        n3 = *(const float4*)(xb + ro3);                            \
        n4 = *(const float4*)(xb + ro4);                            \
        n5 = *(const float4*)(xb + ro5);                            \
        n6 = *(const float4*)(xb + ro6);                            \
        n7 = *(const float4*)(xb + ro7);                            \
    } while (0)

#define DSWRITE() do {                                              \
        *(float4*)(lwb + wo0) = n0;                                 \
        *(float4*)(lwb + wo1) = n1;                                 \
        *(float4*)(lwb + wo2) = n2;                                 \
        *(float4*)(lwb + wo3) = n3;                                 \
        *(float4*)(lwb + wo4) = n4;                                 \
        *(float4*)(lwb + wo5) = n5;                                 \
        *(float4*)(lwb + wo6) = n6;                                 \
        *(float4*)(lwb + wo7) = n7;                                 \
    } while (0)

#define CONSUME(ch) do {                                            \
        _Pragma("unroll")                                           \
        for (int kc = 0; kc < 4; kc++) {                            \
            float4 v0 = *(const float4*)(ra0 + kc * 128);           \
            float4 v1 = *(const float4*)(ra1 + kc * 128);           \
            short8 Ah, Al;                                          \
            split8v(v0, v1, Ah, Al);                                \
            const int ko = (ch) * 128 + kc * 32;                    \
            short8 B0h = *(const short8*)(w0h + ko);                \
            short8 B0l = *(const short8*)(w0l + ko);                \
            short8 B1h = *(const short8*)(w1h + ko);                \
            short8 B1l = *(const short8*)(w1l + ko);                \
            acc0 = __builtin_amdgcn_mfma_f32_16x16x32_bf16(Ah, B0h, acc0, 0, 0, 0); \
            acc1 = __builtin_amdgcn_mfma_f32_16x16x32_bf16(Ah, B1h, acc1, 0, 0, 0); \
            acc0 = __builtin_amdgcn_mfma_f32_16x16x32_bf16(Al, B0h, acc0, 0, 0, 0); \
            acc1 = __builtin_amdgcn_mfma_f32_16x16x32_bf16(Al, B1h, acc1, 0, 0, 0); \
            acc0 = __builtin_amdgcn_mfma_f32_16x16x32_bf16(Ah, B0l, acc0, 0, 0, 0); \
            acc1 = __builtin_amdgcn_mfma_f32_16x16x32_bf16(Ah, B1l, acc1, 0, 0, 0); \
        }                                                           \
    } while (0)

    LOADCH(0);
    DSWRITE();
    LOADCH(1);
    CONSUME(0);
    DSWRITE();
    LOADCH(2);
    CONSUME(1);
    DSWRITE();
    LOADCH(3);
    CONSUME(2);
    DSWRITE();
    CONSUME(3);

#undef LOADCH
#undef DSWRITE
#undef CONSUME

    float b0 = bias[m], b1 = bias[16 + m];
    int nodeBase = rowBase + wave * 16;
#pragma unroll
    for (int rr2 = 0; rr2 < 4; rr2++) {
        int node = nodeBase + quad * 4 + rr2;
        if (node < N) {
            float v0 = acc0[rr2] + b0;
            float v1 = acc1[rr2] + b1;
            float dv = dinv[node];
            h[(size_t)node * OUT_DIM + m]        = v0;
            h[(size_t)node * OUT_DIM + 16 + m]   = v1;
            y0[(size_t)node * OUT_DIM + m]       = (_Float16)(dv * v0);
            y0[(size_t)node * OUT_DIM + 16 + m]  = (_Float16)(dv * v1);
            hy[(size_t)node * OUT_DIM + m]       = (_Float16)(ALPHA * dv * v0);
            hy[(size_t)node * OUT_DIM + 16 + m]  = (_Float16)(ALPHA * dv * v1);
        }
    }
}

// ---------------- propagation: weightless pull on y = dinv*z ----------------
// y_{k+1}[i] = (1-a)*dinv_i^2*(S_i + y_i) + hy_i,   S_i = sum_{j->i} y_j
// z_K[i]     = (1-a)*dinv_i  *(S_i + y_i) + a*h_i   (final step)
// 4 lanes/node x 8ch. csr entry = 4B prescaled byte offset; one int4 load
// covers 4 edges (peel to 4-alignment). 8 z-gathers in flight per iter.
// Bucket-sorted edges keep concurrent gather windows L2-resident.

__global__ __launch_bounds__(256) void k_pull(const int* __restrict__ off4,
                                              const int* __restrict__ csrI,
                                              const _Float16* __restrict__ yprev,
                                              const _Float16* __restrict__ hy,
                                              const float* __restrict__ h,
                                              const float* __restrict__ dinv,
                                              _Float16* __restrict__ ynext,
                                              float* __restrict__ outF, int N) {
    int t = blockIdx.x * 256 + threadIdx.x;
    int node = t >> 2;
    int sub = t & 3;
    int l = sub * 8;
    if (node >= N) return;
    int beg = off4[node * 4];
    int end = off4[node * 4 + 4];
    const char* zb = (const char*)yprev + l * 2;

    float a0[8], a1[8];
#pragma unroll
    for (int c = 0; c < 8; c++) { a0[c] = 0.f; a1[c] = 0.f; }

#define ONE_EDGE(J, A) do {                                                   \
        fp16x8 z_ = *(const fp16x8*)(zb + csrI[J]);                           \
        _Pragma("unroll")                                                     \
        for (int c = 0; c < 8; c++) A[c] += (float)z_[c];                     \
    } while (0)

    int j = beg;
    while ((j & 3) && j < end) { ONE_EDGE(j, a0); j++; }
    for (; j + 8 <= end; j += 8) {
        int4 c0 = *(const int4*)(csrI + j);
        int4 c1 = *(const int4*)(csrI + j + 4);
        fp16x8 z0 = *(const fp16x8*)(zb + c0.x);
        fp16x8 z1 = *(const fp16x8*)(zb + c0.y);
        fp16x8 z2 = *(const fp16x8*)(zb + c0.z);
        fp16x8 z3 = *(const fp16x8*)(zb + c0.w);
        fp16x8 z4 = *(const fp16x8*)(zb + c1.x);
        fp16x8 z5 = *(const fp16x8*)(zb + c1.y);
        fp16x8 z6 = *(const fp16x8*)(zb + c1.z);
        fp16x8 z7 = *(const fp16x8*)(zb + c1.w);
#pragma unroll
        for (int c = 0; c < 8; c++) {
            a0[c] += (float)z0[c];
            a1[c] += (float)z1[c];
            a0[c] += (float)z2[c];
            a1[c] += (float)z3[c];
            a0[c] += (float)z4[c];
            a1[c] += (float)z5[c];
            a0[c] += (float)z6[c];
            a1[c] += (float)z7[c];
        }
    }
    for (; j + 4 <= end; j += 4) {
        int4 c0 = *(const int4*)(csrI + j);
        fp16x8 z0 = *(const fp16x8*)(zb + c0.x);
        fp16x8 z1 = *(const fp16x8*)(zb + c0.y);
        fp16x8 z2 = *(const fp16x8*)(zb + c0.z);
        fp16x8 z3 = *(const fp16x8*)(zb + c0.w);
#pragma unroll
        for (int c = 0; c < 8; c++) {
            a0[c] += (float)z0[c];
            a1[c] += (float)z1[c];
            a0[c] += (float)z2[c];
            a1[c] += (float)z3[c];
        }
    }
    for (; j < end; j++) ONE_EDGE(j, a0);
#undef ONE_EDGE

    float d = dinv[node];
    fp16x8 ys = *(const fp16x8*)((const char*)yprev + (size_t)node * (OUT_DIM * 2) + l * 2);
    if (outF) {
        float od = (1.0f - ALPHA) * d;
        float4 h0 = *(const float4*)(h + (size_t)node * OUT_DIM + l);
        float4 h1 = *(const float4*)(h + (size_t)node * OUT_DIM + l + 4);
        float hh[8] = {h0.x, h0.y, h0.z, h0.w, h1.x, h1.y, h1.z, h1.w};
        float rr[8];
#pragma unroll
        for (int c = 0; c < 8; c++) {
            float s = (a0[c] + a1[c]) + (float)ys[c];
            rr[c] = fmaf(od, s, ALPHA * hh[c]);
        }
        *(float4*)(outF + (size_t)node * OUT_DIM + l)     = make_float4(rr[0], rr[1], rr[2], rr[3]);
        *(float4*)(outF + (size_t)node * OUT_DIM + l + 4) = make_float4(rr[4], rr[5], rr[6], rr[7]);
    } else {
        float og = (1.0f - ALPHA) * d * d;
        fp16x8 hyv = *(const fp16x8*)((const char*)hy + (size_t)node * (OUT_DIM * 2) + l * 2);
        fp16x8 o;
#pragma unroll
        for (int c = 0; c < 8; c++) {
            float s = (a0[c] + a1[c]) + (float)ys[c];
            o[c] = (_Float16)fmaf(og, s, (float)hyv[c]);
        }
        *(fp16x8*)(ynext + (size_t)node * OUT_DIM + l) = o;
    }
}

extern "C" void kernel_launch(void* const* d_in, const int* in_sizes, int n_in,
                              void* d_out, int out_size, void* d_ws, size_t ws_size,
                              hipStream_t stream) {
    const float* x    = (const float*)d_in[0];
    const float* W    = (const float*)d_in[1];
    const float* bias = (const float*)d_in[2];
    const int*   ei   = (const int*)d_in[3];

    const int N = in_sizes[0] / IN_DIM;   // 100000
    const int E = in_sizes[3] / 2;        // 1600000
    const int* src = ei;
    const int* dst = ei + E;
    const int cdiv = (N + 3) / 4;
    const int M = 4 * N;                  // scan length
    const int NB = (M + SCB - 1) / SCB;   // 782 <= 1024
    const int WM = OUT_DIM * IN_DIM;      // 16384

    // workspace layout (each offset 16B-aligned)
    char* ws = (char*)d_ws;
    size_t o = 0;
#define ALLOC(ptr, type, bytes)                         \
    type* ptr = (type*)(ws + o); o += (size_t)(bytes); o = (o + 15) & ~(size_t)15;
    ALLOC(h,    float,    (size_t)N * OUT_DIM * 4)   // 12.8 MB
    ALLOC(yA,   _Float16, (size_t)N * OUT_DIM * 2)   // 6.4 MB
    ALLOC(yB,   _Float16, (size_t)N * OUT_DIM * 2)   // 6.4 MB
    ALLOC(hy,   _Float16, (size_t)N * OUT_DIM * 2)   // 6.4 MB
    ALLOC(csrI, int,      (size_t)E * 4)             // 6.4 MB
    ALLOC(dinv, float,    (size_t)N * 4)
    ALLOC(off4, int,      (size_t)(M + 1) * 4)
    ALLOC(cnt,  int,      (size_t)M * 4)
    ALLOC(cur,  int,      (size_t)M * 4)
    ALLOC(bsum, int,      (size_t)NB * 4)
    ALLOC(boff, int,      (size_t)NB * 4)
    ALLOC(Wh,   short,    (size_t)WM * 2)
    ALLOC(Wl,   short,    (size_t)WM * 2)
#undef ALLOC

    const int B = 256;
    int gN = (N + B - 1) / B;
    int gE = (E + B - 1) / B;
    int gP = ((size_t)N * 4 + B - 1) / B;   // pull grid (1563)
    int gG = (N + 63) / 64;                 // gemm grid (1563)
    int gW = (WM + B - 1) / B;

    hipMemsetAsync(cnt, 0, (size_t)M * 4, stream);
    hipMemsetAsync(cur, 0, (size_t)M * 4, stream);

    // degree + norm + chunked CSR (index-only)
    k_count<<<gE, B, 0, stream>>>(src, dst, cnt, E, cdiv);
    k_rsqrt<<<gN, B, 0, stream>>>(cnt, dinv, N);
    k_bsum<<<NB, SCB, 0, stream>>>(cnt, bsum, M);
    k_bscan<<<1, 1024, 0, stream>>>(bsum, boff, off4 + M, NB);
    k_boff<<<NB, SCB, 0, stream>>>(cnt, boff, off4, M);
    k_fill<<<gE, B, 0, stream>>>(src, dst, off4, cur, csrI, E, cdiv);

    // W bf16-split + dense projection (h fp32, y0 = dinv*h fp16, hy fp16)
    k_wsplit<<<gW, B, 0, stream>>>(W, Wh, Wl, WM);
    k_gemm5<<<gG, B, 0, stream>>>(x, Wh, Wl, bias, dinv, h, yA, hy, N);

    // K propagation steps on y; final step writes fp32 z to d_out
    for (int s = 0; s < KSTEPS; s++) {
        const _Float16* yprev = (s % 2 == 0) ? yA : yB;
        _Float16* ynext = (s % 2 == 0) ? yB : yA;
        float* outF = (s == KSTEPS - 1) ? (float*)d_out : nullptr;
        k_pull<<<gP, B, 0, stream>>>(off4, csrI, yprev, hy, h, dinv, ynext, outF, N);
    }
}

// Round 11
// 728.236 us; speedup vs baseline: 1.0006x; 1.0006x over previous
//
#include <hip/hip_runtime.h>

#define IN_DIM 512
#define OUT_DIM 32
#define KSTEPS 10
#define ALPHA 0.1f
#define SCB 512      // scan block chunk

#define AS1 __attribute__((address_space(1)))
#define AS3 __attribute__((address_space(3)))

typedef __attribute__((ext_vector_type(8))) short short8;    // 8 bf16 (4 VGPRs)
typedef __attribute__((ext_vector_type(4))) float floatx4;   // MFMA acc
typedef _Float16 fp16x8 __attribute__((ext_vector_type(8))); // 16B packed fp16

// ---------------- degree / norm / chunked-CSR build ----------------

__global__ void k_count(const int* __restrict__ src, const int* __restrict__ dst,
                        int* __restrict__ cnt, int E, int cdiv) {
    int e = blockIdx.x * blockDim.x + threadIdx.x;
    if (e < E) {
        int ch = src[e] / cdiv;
        atomicAdd(&cnt[dst[e] * 4 + ch], 1);
    }
}

__global__ void k_rsqrt(const int* __restrict__ cnt, float* __restrict__ dinv, int N) {
    int i = blockIdx.x * blockDim.x + threadIdx.x;
    if (i < N) {
        int d = cnt[4 * i] + cnt[4 * i + 1] + cnt[4 * i + 2] + cnt[4 * i + 3];
        dinv[i] = rsqrtf((float)d + 1.0f);  // +1 self-loop
    }
}

// ---------------- parallel exclusive scan (3 phases) ----------------

__global__ __launch_bounds__(SCB) void k_bsum(const int* __restrict__ v,
                                              int* __restrict__ bsum, int M) {
    __shared__ int s[SCB];
    int i = blockIdx.x * SCB + threadIdx.x;
    s[threadIdx.x] = (i < M) ? v[i] : 0;
    __syncthreads();
    for (int d = SCB / 2; d > 0; d >>= 1) {
        if (threadIdx.x < d) s[threadIdx.x] += s[threadIdx.x + d];
        __syncthreads();
    }
    if (threadIdx.x == 0) bsum[blockIdx.x] = s[0];
}

__global__ __launch_bounds__(1024) void k_bscan(const int* __restrict__ bsum,
                                                int* __restrict__ bsum_off,
                                                int* __restrict__ total_out, int NB) {
    __shared__ int s[1024];
    int t = threadIdx.x;
    s[t] = (t < NB) ? bsum[t] : 0;
    __syncthreads();
    for (int d = 1; d < 1024; d <<= 1) {
        int v = (t >= d) ? s[t - d] : 0;
        __syncthreads();
        s[t] += v;
        __syncthreads();
    }
    if (t < NB) bsum_off[t] = (t == 0) ? 0 : s[t - 1];
    if (t == 0 && total_out) *total_out = s[1023];
}

__global__ __launch_bounds__(SCB) void k_boff(const int* __restrict__ v,
                                              const int* __restrict__ bsum_off,
                                              int* __restrict__ off, int M) {
    __shared__ int s[SCB];
    int t = threadIdx.x;
    int i = blockIdx.x * SCB + t;
    int myv = (i < M) ? v[i] : 0;
    s[t] = myv;
    __syncthreads();
    for (int d = 1; d < SCB; d <<= 1) {
        int u = (t >= d) ? s[t - d] : 0;
        __syncthreads();
        s[t] += u;
        __syncthreads();
    }
    if (i < M) off[i] = bsum_off[blockIdx.x] + s[t] - myv;  // exclusive
}

// csr entry: byte offset of src y-row (src*64). No weights (y-substitution).
__global__ void k_fill(const int* __restrict__ src, const int* __restrict__ dst,
                       const int* __restrict__ off4,
                       int* __restrict__ cur, int* __restrict__ csrI, int E, int cdiv) {
    int e = blockIdx.x * blockDim.x + threadIdx.x;
    if (e < E) {
        int d = dst[e], s = src[e];
        int key = d * 4 + s / cdiv;
        int pos = off4[key] + atomicAdd(&cur[key], 1);
        csrI[pos] = s * (OUT_DIM * 2);
    }
}

// ---------------- bf16 split helpers ----------------

__device__ inline unsigned bf16_rne(float f) {
    unsigned u = __float_as_uint(f);
    return (u + 0x7FFFu + ((u >> 16) & 1u)) >> 16;
}

__global__ void k_wsplit(const float* __restrict__ W, short* __restrict__ Wh,
                         short* __restrict__ Wl, int M) {
    int i = blockIdx.x * blockDim.x + threadIdx.x;
    if (i < M) {
        float f = W[i];
        unsigned hb = bf16_rne(f);
        float fh = __uint_as_float(hb << 16);
        unsigned lb = bf16_rne(f - fh);
        Wh[i] = (short)hb;
        Wl[i] = (short)lb;
    }
}

__device__ inline void split8v(float4 v0, float4 v1, short8& hi, short8& lo) {
    float fv[8] = {v0.x, v0.y, v0.z, v0.w, v1.x, v1.y, v1.z, v1.w};
#pragma unroll
    for (int j = 0; j < 8; j++) {
        unsigned hb = bf16_rne(fv[j]);
        float fh = __uint_as_float(hb << 16);
        unsigned lb = bf16_rne(fv[j] - fh);
        hi[j] = (short)hb;
        lo[j] = (short)lb;
    }
}

// ---------------- dense projection: global_load_lds-staged MFMA ----------------
// Per-wave private 16-row tile, K in 8 chunks of 256B/row. Staging is DMA:
// __builtin_amdgcn_global_load_lds width=16 (Common-mistake #1 fix) — no
// VGPR round-trip, no vmcnt(0) drain. LDS dest is linear (rule #21): the
// XOR swizzle (col ^ (row&7)<<4, bits 4-6) is applied to the per-lane
// GLOBAL source address and on the ds_read side; read is <=2 lanes/bank.
// Counted waits: invariant 12 outstanding (4 stage + 8 B-frag loads);
// per chunk issue {8 B(ch+1), 4 stage(ch+1)} then s_waitcnt vmcnt(12).
// B fragments double-buffered in registers. Zero barriers.

#define WAITV(n) asm volatile("s_waitcnt vmcnt(" #n ")" ::: "memory")

__global__ __launch_bounds__(256) void k_gemm6(const float* __restrict__ x,
                                               const short* __restrict__ Wh,
                                               const short* __restrict__ Wl,
                                               const float* __restrict__ bias,
                                               const float* __restrict__ dinv,
                                               float* __restrict__ h,
                                               _Float16* __restrict__ y0,
                                               _Float16* __restrict__ hy, int N) {
    __shared__ char lds[4][2][4096];   // [wave][buf][16 rows x 256B]
    const int t = threadIdx.x;
    const int wave = t >> 6, lane = t & 63;
    const int m = lane & 15, quad = lane >> 4;
    const int rowBase = blockIdx.x * 64 + wave * 16;

    // per-lane stage source byte offsets (chunk 0); chunk ch adds ch*256.
    // stage instr k: lane l -> row 4k+(l>>4), within-row byte (l&15)*16,
    // source col pre-swizzled by ^((row&7)<<4).
    const int srow = lane >> 4;          // 0..3
    const int scol = (lane & 15) * 16;   // 0..240
    long so0, so1, so2, so3;
    {
        int rl, r;
#define MKSO(k, v)                                                        \
        rl = 4 * (k) + srow;                                              \
        r = rowBase + rl; if (r >= N) r = N - 1;                          \
        v = (long)r * (IN_DIM * 4) + (scol ^ ((rl & 7) << 4));
        MKSO(0, so0) MKSO(1, so1) MKSO(2, so2) MKSO(3, so3)
#undef MKSO
    }
    const char* xb = (const char*)x;
    char* wb0 = &lds[wave][0][0];
    char* wb1 = &lds[wave][1][0];

    // ds_read bases (swizzled) for the MFMA A-fragments
    const int key = (m & 7) << 4;
    const int rb = m * 256;

    const short* w0h = Wh + (size_t)m * IN_DIM + quad * 8;          // outs 0..15
    const short* w0l = Wl + (size_t)m * IN_DIM + quad * 8;
    const short* w1h = Wh + (size_t)(m + 16) * IN_DIM + quad * 8;   // outs 16..31
    const short* w1l = Wl + (size_t)(m + 16) * IN_DIM + quad * 8;

    floatx4 acc0 = {0.f, 0.f, 0.f, 0.f};
    floatx4 acc1 = {0.f, 0.f, 0.f, 0.f};

#define STAGE(ch, buf) do {                                               \
        __builtin_amdgcn_global_load_lds(                                 \
            (const AS1 void*)(xb + so0 + (ch) * 256),                     \
            (AS3 void*)((buf) + 0 * 1024), 16, 0, 0);                     \
        __builtin_amdgcn_global_load_lds(                                 \
            (const AS1 void*)(xb + so1 + (ch) * 256),                     \
            (AS3 void*)((buf) + 1 * 1024), 16, 0, 0);                     \
        __builtin_amdgcn_global_load_lds(                                 \
            (const AS1 void*)(xb + so2 + (ch) * 256),                     \
            (AS3 void*)((buf) + 2 * 1024), 16, 0, 0);                     \
        __builtin_amdgcn_global_load_lds(                                 \
            (const AS1 void*)(xb + so3 + (ch) * 256),                     \
            (AS3 void*)((buf) + 3 * 1024), 16, 0, 0);                     \
    } while (0)

#define BLOAD(ch, B0h0, B0l0, B1h0, B1l0, B0h1, B0l1, B1h1, B1l1) do {    \
        const int ko0 = (ch) * 64;                                        \
        const int ko1 = (ch) * 64 + 32;                                   \
        B0h0 = *(const short8*)(w0h + ko0);                               \
        B0l0 = *(const short8*)(w0l + ko0);                               \
        B1h0 = *(const short8*)(w1h + ko0);                               \
        B1l0 = *(const short8*)(w1l + ko0);                               \
        B0h1 = *(const short8*)(w0h + ko1);                               \
        B0l1 = *(const short8*)(w0l + ko1);                               \
        B1h1 = *(const short8*)(w1h + ko1);                               \
        B1l1 = *(const short8*)(w1l + ko1);                               \
    } while (0)

#define CONSUME1(buf, kc, Bh0, Bl0, Bh1, Bl1) do {                        \
        int o0 = rb + (((kc) * 128 + quad * 32) ^ key);                   \
        int o1 = rb + (((kc) * 128 + quad * 32 + 16) ^ key);              \
        float4 v0 = *(const float4*)((buf) + o0);                         \
        float4 v1 = *(const float4*)((buf) + o1);                         \
        short8 Ah, Al;                                                    \
        split8v(v0, v1, Ah, Al);                                          \
        acc0 = __builtin_amdgcn_mfma_f32_16x16x32_bf16(Ah, Bh0, acc0, 0, 0, 0); \
        acc1 = __builtin_amdgcn_mfma_f32_16x16x32_bf16(Ah, Bh1, acc1, 0, 0, 0); \
        acc0 = __builtin_amdgcn_mfma_f32_16x16x32_bf16(Al, Bh0, acc0, 0, 0, 0); \
        acc1 = __builtin_amdgcn_mfma_f32_16x16x32_bf16(Al, Bh1, acc1, 0, 0, 0); \
        acc0 = __builtin_amdgcn_mfma_f32_16x16x32_bf16(Ah, Bl0, acc0, 0, 0, 0); \
        acc1 = __builtin_amdgcn_mfma_f32_16x16x32_bf16(Ah, Bl1, acc1, 0, 0, 0); \
    } while (0)

    short8 a0h0, a0l0, a1h0, a1l0, a0h1, a0l1, a1h1, a1l1;  // B set A
    short8 b0h0, b0l0, b1h0, b1l0, b0h1, b0l1, b1h1, b1l1;  // B set B

    // prologue: stage chunk0, load B(0) into set A   -> 12 outstanding
    STAGE(0, wb0);
    BLOAD(0, a0h0, a0l0, a1h0, a1l0, a0h1, a0l1, a1h1, a1l1);

    // iter ch: issue B(ch+1)+STAGE(ch+1), wait vmcnt(12), consume ch
#define ITER_A(ch, curbuf, nextbuf) /* consumes set A, loads set B */     \
    BLOAD((ch) + 1, b0h0, b0l0, b1h0, b1l0, b0h1, b0l1, b1h1, b1l1);      \
    STAGE((ch) + 1, nextbuf);                                             \
    WAITV(12);                                                            \
    CONSUME1(curbuf, 0, a0h0, a0l0, a1h0, a1l0);                          \
    CONSUME1(curbuf, 1, a0h1, a0l1, a1h1, a1l1);

#define ITER_B(ch, curbuf, nextbuf) /* consumes set B, loads set A */     \
    BLOAD((ch) + 1, a0h0, a0l0, a1h0, a1l0, a0h1, a0l1, a1h1, a1l1);      \
    STAGE((ch) + 1, nextbuf);                                             \
    WAITV(12);                                                            \
    CONSUME1(curbuf, 0, b0h0, b0l0, b1h0, b1l0);                          \
    CONSUME1(curbuf, 1, b0h1, b0l1, b1h1, b1l1);

    ITER_A(0, wb0, wb1)
    ITER_B(1, wb1, wb0)
    ITER_A(2, wb0, wb1)
    ITER_B(3, wb1, wb0)
    ITER_A(4, wb0, wb1)
    ITER_B(5, wb1, wb0)
    ITER_A(6, wb0, wb1)
    // last chunk: nothing left to issue; drain fully
    WAITV(0);
    CONSUME1(wb1, 0, b0h0, b0l0, b1h0, b1l0);
    CONSUME1(wb1, 1, b0h1, b0l1, b1h1, b1l1);

#undef ITER_A
#undef ITER_B
#undef STAGE
#undef BLOAD
#undef CONSUME1

    // C/D layout: col = lane&15 (out), row = quad*4 + reg (node)
    float b0 = bias[m], b1 = bias[16 + m];
#pragma unroll
    for (int rr2 = 0; rr2 < 4; rr2++) {
        int node = rowBase + quad * 4 + rr2;
        if (node < N) {
            float v0 = acc0[rr2] + b0;
            float v1 = acc1[rr2] + b1;
            float dv = dinv[node];
            h[(size_t)node * OUT_DIM + m]        = v0;
            h[(size_t)node * OUT_DIM + 16 + m]   = v1;
            y0[(size_t)node * OUT_DIM + m]       = (_Float16)(dv * v0);
            y0[(size_t)node * OUT_DIM + 16 + m]  = (_Float16)(dv * v1);
            hy[(size_t)node * OUT_DIM + m]       = (_Float16)(ALPHA * dv * v0);
            hy[(size_t)node * OUT_DIM + 16 + m]  = (_Float16)(ALPHA * dv * v1);
        }
    }
}

// ---------------- propagation: weightless pull on y = dinv*z ----------------
// (unchanged — passed at 728.7 baseline)

__global__ __launch_bounds__(256) void k_pull(const int* __restrict__ off4,
                                              const int* __restrict__ csrI,
                                              const _Float16* __restrict__ yprev,
                                              const _Float16* __restrict__ hy,
                                              const float* __restrict__ h,
                                              const float* __restrict__ dinv,
                                              _Float16* __restrict__ ynext,
                                              float* __restrict__ outF, int N) {
    int t = blockIdx.x * 256 + threadIdx.x;
    int node = t >> 2;
    int sub = t & 3;
    int l = sub * 8;
    if (node >= N) return;
    int beg = off4[node * 4];
    int end = off4[node * 4 + 4];
    const char* zb = (const char*)yprev + l * 2;

    float a0[8], a1[8];
#pragma unroll
    for (int c = 0; c < 8; c++) { a0[c] = 0.f; a1[c] = 0.f; }

#define ONE_EDGE(J, A) do {                                                   \
        fp16x8 z_ = *(const fp16x8*)(zb + csrI[J]);                           \
        _Pragma("unroll")                                                     \
        for (int c = 0; c < 8; c++) A[c] += (float)z_[c];                     \
    } while (0)

    int j = beg;
    while ((j & 3) && j < end) { ONE_EDGE(j, a0); j++; }
    for (; j + 8 <= end; j += 8) {
        int4 c0 = *(const int4*)(csrI + j);
        int4 c1 = *(const int4*)(csrI + j + 4);
        fp16x8 z0 = *(const fp16x8*)(zb + c0.x);
        fp16x8 z1 = *(const fp16x8*)(zb + c0.y);
        fp16x8 z2 = *(const fp16x8*)(zb + c0.z);
        fp16x8 z3 = *(const fp16x8*)(zb + c0.w);
        fp16x8 z4 = *(const fp16x8*)(zb + c1.x);
        fp16x8 z5 = *(const fp16x8*)(zb + c1.y);
        fp16x8 z6 = *(const fp16x8*)(zb + c1.z);
        fp16x8 z7 = *(const fp16x8*)(zb + c1.w);
#pragma unroll
        for (int c = 0; c < 8; c++) {
            a0[c] += (float)z0[c];
            a1[c] += (float)z1[c];
            a0[c] += (float)z2[c];
            a1[c] += (float)z3[c];
            a0[c] += (float)z4[c];
            a1[c] += (float)z5[c];
            a0[c] += (float)z6[c];
            a1[c] += (float)z7[c];
        }
    }
    for (; j + 4 <= end; j += 4) {
        int4 c0 = *(const int4*)(csrI + j);
        fp16x8 z0 = *(const fp16x8*)(zb + c0.x);
        fp16x8 z1 = *(const fp16x8*)(zb + c0.y);
        fp16x8 z2 = *(const fp16x8*)(zb + c0.z);
        fp16x8 z3 = *(const fp16x8*)(zb + c0.w);
#pragma unroll
        for (int c = 0; c < 8; c++) {
            a0[c] += (float)z0[c];
            a1[c] += (float)z1[c];
            a0[c] += (float)z2[c];
            a1[c] += (float)z3[c];
        }
    }
    for (; j < end; j++) ONE_EDGE(j, a0);
#undef ONE_EDGE

    float d = dinv[node];
    fp16x8 ys = *(const fp16x8*)((const char*)yprev + (size_t)node * (OUT_DIM * 2) + l * 2);
    if (outF) {
        float od = (1.0f - ALPHA) * d;
        float4 h0 = *(const float4*)(h + (size_t)node * OUT_DIM + l);
        float4 h1 = *(const float4*)(h + (size_t)node * OUT_DIM + l + 4);
        float hh[8] = {h0.x, h0.y, h0.z, h0.w, h1.x, h1.y, h1.z, h1.w};
        float rr[8];
#pragma unroll
        for (int c = 0; c < 8; c++) {
            float s = (a0[c] + a1[c]) + (float)ys[c];
            rr[c] = fmaf(od, s, ALPHA * hh[c]);
        }
        *(float4*)(outF + (size_t)node * OUT_DIM + l)     = make_float4(rr[0], rr[1], rr[2], rr[3]);
        *(float4*)(outF + (size_t)node * OUT_DIM + l + 4) = make_float4(rr[4], rr[5], rr[6], rr[7]);
    } else {
        float og = (1.0f - ALPHA) * d * d;
        fp16x8 hyv = *(const fp16x8*)((const char*)hy + (size_t)node * (OUT_DIM * 2) + l * 2);
        fp16x8 o;
#pragma unroll
        for (int c = 0; c < 8; c++) {
            float s = (a0[c] + a1[c]) + (float)ys[c];
            o[c] = (_Float16)fmaf(og, s, (float)hyv[c]);
        }
        *(fp16x8*)(ynext + (size_t)node * OUT_DIM + l) = o;
    }
}

extern "C" void kernel_launch(void* const* d_in, const int* in_sizes, int n_in,
                              void* d_out, int out_size, void* d_ws, size_t ws_size,
                              hipStream_t stream) {
    const float* x    = (const float*)d_in[0];
    const float* W    = (const float*)d_in[1];
    const float* bias = (const float*)d_in[2];
    const int*   ei   = (const int*)d_in[3];

    const int N = in_sizes[0] / IN_DIM;   // 100000
    const int E = in_sizes[3] / 2;        // 1600000
    const int* src = ei;
    const int* dst = ei + E;
    const int cdiv = (N + 3) / 4;
    const int M = 4 * N;                  // scan length
    const int NB = (M + SCB - 1) / SCB;   // 782 <= 1024
    const int WM = OUT_DIM * IN_DIM;      // 16384

    // workspace layout (each offset 16B-aligned)
    char* ws = (char*)d_ws;
    size_t o = 0;
#define ALLOC(ptr, type, bytes)                         \
    type* ptr = (type*)(ws + o); o += (size_t)(bytes); o = (o + 15) & ~(size_t)15;
    ALLOC(h,    float,    (size_t)N * OUT_DIM * 4)   // 12.8 MB
    ALLOC(yA,   _Float16, (size_t)N * OUT_DIM * 2)   // 6.4 MB
    ALLOC(yB,   _Float16, (size_t)N * OUT_DIM * 2)   // 6.4 MB
    ALLOC(hy,   _Float16, (size_t)N * OUT_DIM * 2)   // 6.4 MB
    ALLOC(csrI, int,      (size_t)E * 4)             // 6.4 MB
    ALLOC(dinv, float,    (size_t)N * 4)
    ALLOC(off4, int,      (size_t)(M + 1) * 4)
    ALLOC(cnt,  int,      (size_t)M * 4)
    ALLOC(cur,  int,      (size_t)M * 4)
    ALLOC(bsum, int,      (size_t)NB * 4)
    ALLOC(boff, int,      (size_t)NB * 4)
    ALLOC(Wh,   short,    (size_t)WM * 2)
    ALLOC(Wl,   short,    (size_t)WM * 2)
#undef ALLOC

    const int B = 256;
    int gN = (N + B - 1) / B;
    int gE = (E + B - 1) / B;
    int gP = ((size_t)N * 4 + B - 1) / B;   // pull grid (1563)
    int gG = (N + 63) / 64;                 // gemm grid (1563)
    int gW = (WM + B - 1) / B;

    hipMemsetAsync(cnt, 0, (size_t)M * 4, stream);
    hipMemsetAsync(cur, 0, (size_t)M * 4, stream);

    // degree + norm + chunked CSR (index-only)
    k_count<<<gE, B, 0, stream>>>(src, dst, cnt, E, cdiv);
    k_rsqrt<<<gN, B, 0, stream>>>(cnt, dinv, N);
    k_bsum<<<NB, SCB, 0, stream>>>(cnt, bsum, M);
    k_bscan<<<1, 1024, 0, stream>>>(bsum, boff, off4 + M, NB);
    k_boff<<<NB, SCB, 0, stream>>>(cnt, boff, off4, M);
    k_fill<<<gE, B, 0, stream>>>(src, dst, off4, cur, csrI, E, cdiv);

    // W bf16-split + dense projection (h fp32, y0 = dinv*h fp16, hy fp16)
    k_wsplit<<<gW, B, 0, stream>>>(W, Wh, Wl, WM);
    k_gemm6<<<gG, B, 0, stream>>>(x, Wh, Wl, bias, dinv, h, yA, hy, N);

    // K propagation steps on y; final step writes fp32 z to d_out
    for (int s = 0; s < KSTEPS; s++) {
        const _Float16* yprev = (s % 2 == 0) ? yA : yB;
        _Float16* ynext = (s % 2 == 0) ? yB : yA;
        float* outF = (s == KSTEPS - 1) ? (float*)d_out : nullptr;
        k_pull<<<gP, B, 0, stream>>>(off4, csrI, yprev, hy, h, dinv, ynext, outF, N);
    }
}